// Round 6
// baseline (365.084 us; speedup 1.0000x reference)
//
#include <hip/hip_runtime.h>
#include <hip/hip_bf16.h>

// GlobalAttn: x = lrelu(concat(q,k) @ w1^T + b1); attn[e,h] = x[e,h,:]·w2[h,:];
// out = segment_softmax(attn, index). E=320000, D=256, K=512, H=4, N=10000.
//
// Structure (R6): B (w1, 256 KB bf16) is pre-packed into MFMA-fragment order
// and read per-use as ONE coalesced global_load_dwordx4 per wave from L2 --
// no B LDS, no B staging, no B barriers. LDS holds only A ([128][64] bf16,
// XOR-swizzled, double-buffered, 32 KB) -> 2 blocks/CU, 16 waves/CU TLP.
// All vmem ops are register loads, so the inter-step barrier needs only
// lgkmcnt(0) (ds_write visibility) -- vmcnt is NEVER drained at barriers;
// the compiler inserts exact per-use waits for its own register loads.
// A prefetch: global->reg at step u-1, cvt+ds_write at step u (buffer u+1).
// Tile: BM=128, BN=256(full), BK=64, 8 steps/tile, 2 tiles/block, grid 1250.
// 8 waves as 2M x 4N: wave tile 64x64 (head wn), acc[4][4] = 64 VGPR.

typedef __attribute__((ext_vector_type(8))) short bf16x8;
typedef __attribute__((ext_vector_type(4))) float f32x4;

#define NNODES 10000
#define NT     2500    // 128-row M-tiles
#define TPB    2       // tiles per block
#define GRID   (NT / TPB)

__device__ __forceinline__ short f2bf(float f) {
    __hip_bfloat16 h = __float2bfloat16(f);   // RNE
    return *reinterpret_cast<short*>(&h);
}

// ---- B prep: fragment-ordered bf16 (one-time, tiny) ----
// wf[((c*16+s32)*64 + lane)*8 + j] = bf16( w1[c*16 + (lane&15)][s32*32 + (lane>>4)*8 + j] )
// so a wave's B-frag (colblk c, 32-k-slice s32) is 64 lanes x 16 B contiguous.
__global__ void w1_frag(const float* __restrict__ w1, short* __restrict__ wf) {
    int bid = blockIdx.x;            // 0..255 = c*16 + s32
    int l   = threadIdx.x;           // 0..63
    int n = (bid >> 4) * 16 + (l & 15);
    int k = (bid & 15) * 32 + (l >> 4) * 8;
    const float* src = w1 + (size_t)n * 512 + k;
    float4 v0 = *(const float4*)src;
    float4 v1 = *(const float4*)(src + 4);
    bf16x8 pk;
    pk[0]=f2bf(v0.x); pk[1]=f2bf(v0.y); pk[2]=f2bf(v0.z); pk[3]=f2bf(v0.w);
    pk[4]=f2bf(v1.x); pk[5]=f2bf(v1.y); pk[6]=f2bf(v1.z); pk[7]=f2bf(v1.w);
    *(bf16x8*)(wf + ((size_t)bid * 64 + l) * 8) = pk;
}

__global__ void seg_init(float* __restrict__ segsum, int n) {
    int i = blockIdx.x * blockDim.x + threadIdx.x;
    if (i < n) segsum[i] = 0.f;
}

// ---------------- main fused GEMM + epilogue ----------------
__global__ __launch_bounds__(512, 4) void attn_gemm(
    const float* __restrict__ q, const float* __restrict__ kk_,
    const short* __restrict__ wf, const float* __restrict__ b1,
    const float* __restrict__ w2, const int* __restrict__ index,
    float* __restrict__ attn, float* __restrict__ segsum)
{
    __shared__ short lds_a[2][128 * 64];   // 16 KB per buf

    const int tid  = threadIdx.x;
    const int lane = tid & 63;
    const int w    = tid >> 6;
    const int wm   = w >> 2;          // 0..1 (M)
    const int wn   = w & 3;           // 0..3 (N == head)
    const int l15  = lane & 15;
    const int lhi  = lane >> 4;

    // A staging: thread t -> row rt = t>>2, 16 floats at chunk kcg=(t&3)*2
    const int rt  = tid >> 2;
    const int kcg = (tid & 3) * 2;
    const int wbyte0 = rt * 128 + ((((kcg + 0) * 16)) ^ ((rt & 7) << 4));
    const int wbyte1 = rt * 128 + ((((kcg + 1) * 16)) ^ ((rt & 7) << 4));

    float4 ar[4];                     // A(u+1) staging regs

    f32x4 acc[4][4];

    float bias[4], w2v[4];
#pragma unroll
    for (int fn = 0; fn < 4; ++fn) {
        int col = wn * 64 + fn * 16 + l15;
        bias[fn] = b1[col];
        w2v[fn]  = w2[col];
    }

#define LOADA(T, S) {                                                           \
        const float* bp = ((S) < 4) ? q : kk_;                                  \
        const float* p  = bp + (size_t)((T) * 128 + rt) * 256                   \
                             + ((S) & 3) * 64 + (tid & 3) * 16;                 \
        ar[0] = *(const float4*)p;      ar[1] = *(const float4*)(p + 4);        \
        ar[2] = *(const float4*)(p + 8); ar[3] = *(const float4*)(p + 12);      \
    }
#define CVTWRITE(wb) {                                                          \
        bf16x8 p0, p1;                                                          \
        p0[0]=f2bf(ar[0].x); p0[1]=f2bf(ar[0].y); p0[2]=f2bf(ar[0].z); p0[3]=f2bf(ar[0].w); \
        p0[4]=f2bf(ar[1].x); p0[5]=f2bf(ar[1].y); p0[6]=f2bf(ar[1].z); p0[7]=f2bf(ar[1].w); \
        p1[0]=f2bf(ar[2].x); p1[1]=f2bf(ar[2].y); p1[2]=f2bf(ar[2].z); p1[3]=f2bf(ar[2].w); \
        p1[4]=f2bf(ar[3].x); p1[5]=f2bf(ar[3].y); p1[6]=f2bf(ar[3].z); p1[7]=f2bf(ar[3].w); \
        *(bf16x8*)((char*)&lds_a[wb][0] + wbyte0) = p0;                         \
        *(bf16x8*)((char*)&lds_a[wb][0] + wbyte1) = p1;                         \
    }
#define FRAGMFMA(rb, s) {                                                       \
        _Pragma("unroll")                                                       \
        for (int ks = 0; ks < 2; ++ks) {                                        \
            bf16x8 bfr[4], afr[4];                                              \
            _Pragma("unroll")                                                   \
            for (int fn = 0; fn < 4; ++fn)                                      \
                bfr[fn] = *(const bf16x8*)(wf +                                 \
                    (((size_t)((wn * 4 + fn) * 16 + (s) * 2 + ks) * 64 + lane) * 8)); \
            _Pragma("unroll")                                                   \
            for (int fm = 0; fm < 4; ++fm) {                                    \
                const int r = wm * 64 + fm * 16 + l15;                          \
                afr[fm] = *(const bf16x8*)((const char*)&lds_a[rb][0]           \
                    + r * 128 + ((((ks * 4 + lhi) * 16)) ^ ((r & 7) << 4)));    \
            }                                                                   \
            _Pragma("unroll")                                                   \
            for (int fm = 0; fm < 4; ++fm)                                      \
                _Pragma("unroll")                                               \
                for (int fn = 0; fn < 4; ++fn)                                  \
                    acc[fm][fn] = __builtin_amdgcn_mfma_f32_16x16x32_bf16(      \
                        afr[fm], bfr[fn], acc[fm][fn], 0, 0, 0);                \
        }                                                                       \
    }
#define BAR() {                                                                 \
        asm volatile("s_waitcnt lgkmcnt(0)" ::: "memory");                      \
        __builtin_amdgcn_s_barrier();                                           \
    }

    const int tile0 = blockIdx.x * TPB;

    // ---- prologue: buf0 <- (tile0,0); ar <- (tile0,1) ----
    LOADA(tile0, 0);
    CVTWRITE(0);
    LOADA(tile0, 1);
    BAR();

#pragma unroll
    for (int ti = 0; ti < TPB; ++ti) {
        const int tile  = tile0 + ti;
        const int tnext = tile0 + ((ti + 1 < TPB) ? ti + 1 : ti);  // clamp (in-bounds)

#pragma unroll
        for (int i = 0; i < 4; ++i)
#pragma unroll
            for (int j = 0; j < 4; ++j) acc[i][j] = (f32x4){0.f, 0.f, 0.f, 0.f};

#pragma unroll
        for (int s = 0; s < 8; ++s) {
            const int rb = s & 1, wb = rb ^ 1;
            CVTWRITE(wb);                          // A(u+1), loaded last step
            // load A(u+2)
            if (s < 6) { LOADA(tile, s + 2); }
            else       { LOADA(tnext, s - 6); }
            FRAGMFMA(rb, s);
            BAR();
        }

        // ---- epilogue: bias + lrelu + dot(w2) + exp + atomicAdd(segsum) ----
#pragma unroll
        for (int fm = 0; fm < 4; ++fm) {
#pragma unroll
            for (int r = 0; r < 4; ++r) {
                int row = tile * 128 + wm * 64 + fm * 16 + lhi * 4 + r;
                float p = 0.f;
#pragma unroll
                for (int fn = 0; fn < 4; ++fn) {
                    float y = acc[fm][fn][r] + bias[fn];
                    y = (y > 0.f) ? y : 0.01f * y;
                    p += y * w2v[fn];
                }
#pragma unroll
                for (int m = 1; m < 16; m <<= 1) p += __shfl_xor(p, m);
                if (l15 == 0) {
                    float e = __expf(p);
                    attn[(size_t)row * 4 + wn] = e;
                    atomicAdd(&segsum[index[row] * 4 + wn], e);
                }
            }
        }
    }

#undef LOADA
#undef CVTWRITE
#undef FRAGMFMA
#undef BAR
}

__global__ void seg_norm(const float* __restrict__ attn, const int* __restrict__ index,
                         const float* __restrict__ segsum, float* __restrict__ out, int total) {
    int i = blockIdx.x * blockDim.x + threadIdx.x;
    if (i >= total) return;
    int e = i >> 2, h = i & 3;
    out[i] = attn[i] / (segsum[index[e] * 4 + h] + 1e-16f);
}

extern "C" void kernel_launch(void* const* d_in, const int* in_sizes, int n_in,
                              void* d_out, int out_size, void* d_ws, size_t ws_size,
                              hipStream_t stream) {
    const float* q   = (const float*)d_in[0];
    const float* k   = (const float*)d_in[1];
    const float* w1  = (const float*)d_in[2];
    const float* b1  = (const float*)d_in[3];
    const float* w2  = (const float*)d_in[4];
    const int* index = (const int*)d_in[5];

    const int nE = in_sizes[0] / 256;      // 320000
    char* ws = (char*)d_ws;
    float* attn   = (float*)ws;            ws += (size_t)nE * 4 * 4;
    float* segsum = (float*)ws;            ws += (size_t)NNODES * 4 * 4;
    short* wf     = (short*)ws;            // 256*512 bf16 = 256KB, frag-ordered
    float* out    = (float*)d_out;

    w1_frag<<<256, 64, 0, stream>>>(w1, wf);
    seg_init<<<(NNODES * 4 + 255) / 256, 256, 0, stream>>>(segsum, NNODES * 4);

    attn_gemm<<<GRID, 512, 0, stream>>>(q, k, wf, b1, w2, index, attn, segsum);

    int total = nE * 4;
    seg_norm<<<(total + 255) / 256, 256, 0, stream>>>(attn, index, segsum, out, total);
}

// Round 7
// 324.073 us; speedup vs baseline: 1.1265x; 1.1265x over previous
//
#include <hip/hip_runtime.h>
#include <hip/hip_bf16.h>

// GlobalAttn: x = lrelu(concat(q,k) @ w1^T + b1); attn[e,h] = x[e,h,:]·w2[h,:];
// out = segment_softmax(attn, index). E=320000, D=256, K=512, H=4, N=10000.
//
// R7: latency-oriented structure. Facts: MFMA total 10us, LDS 20us, HBM 104us
// -> purely HBM/orchestration bound. Design: block=256thr (4 waves = 4 heads),
// BM=64, BN=256 (A read ONCE), BK=32, 16 steps, grid 5000.
//  * B (w1) pre-packed in MFMA-fragment order; read per-use as one coalesced
//    16B/lane global load from L2 (256 KB, hot in every XCD). No B staging.
//  * A: only LDS user. fp32 global -> regs (PD=3 slots, 24 VGPR) -> cvt ->
//    swizzled ds_write one step ahead -> ds_read_b128 frags. Swizzle
//    chunk ^= (row>>1)&3 gives minimum-phase (conflict-free) write AND read.
//  * NO global_load_lds anywhere -> inter-step barrier is raw
//    s_waitcnt lgkmcnt(0) + s_barrier; vmem queue (A prefetch) is NEVER
//    drained by a barrier. Compiler inserts exact per-use vmcnt waits.
//  * VGPR budget: acc 64 + ar 24 + transients ~20 + addr ~12 < 128 ->
//    launch_bounds(256,4): 4 blocks/CU, 16 waves/CU, ~96 KB A in flight/CU.

typedef __attribute__((ext_vector_type(8))) short bf16x8;
typedef __attribute__((ext_vector_type(4))) float f32x4;

#define NNODES 10000

__device__ __forceinline__ short f2bf(float f) {
    __hip_bfloat16 h = __float2bfloat16(f);   // RNE
    return *reinterpret_cast<short*>(&h);
}

// ---- B prep: fragment-ordered bf16 (one-time, tiny) ----
// frag f = c*16 + s32 (c: 16-col block, s32: 32-k slice).
// wf[(f*64 + lane)*8 + j] = bf16( w1[c*16 + (lane&15)][s32*32 + (lane>>4)*8 + j] )
__global__ void w1_frag(const float* __restrict__ w1, short* __restrict__ wf) {
    int bid = blockIdx.x;            // 0..255
    int l   = threadIdx.x;           // 0..63
    int n = (bid >> 4) * 16 + (l & 15);
    int k = (bid & 15) * 32 + (l >> 4) * 8;
    const float* src = w1 + (size_t)n * 512 + k;
    float4 v0 = *(const float4*)src;
    float4 v1 = *(const float4*)(src + 4);
    bf16x8 pk;
    pk[0]=f2bf(v0.x); pk[1]=f2bf(v0.y); pk[2]=f2bf(v0.z); pk[3]=f2bf(v0.w);
    pk[4]=f2bf(v1.x); pk[5]=f2bf(v1.y); pk[6]=f2bf(v1.z); pk[7]=f2bf(v1.w);
    *(bf16x8*)(wf + ((size_t)bid * 64 + l) * 8) = pk;
}

__global__ void seg_init(float* __restrict__ segsum, int n) {
    int i = blockIdx.x * blockDim.x + threadIdx.x;
    if (i < n) segsum[i] = 0.f;
}

// ---------------- main fused GEMM + epilogue ----------------
__global__ __launch_bounds__(256, 4) void attn_gemm(
    const float* __restrict__ q, const float* __restrict__ kk_,
    const short* __restrict__ wf, const float* __restrict__ b1,
    const float* __restrict__ w2, const int* __restrict__ index,
    float* __restrict__ attn, float* __restrict__ segsum)
{
    __shared__ short lds_a[2][64 * 32];   // 4 KB per buf

    const int tid  = threadIdx.x;
    const int lane = tid & 63;
    const int wn   = tid >> 6;        // wave = head 0..3
    const int l15  = lane & 15;
    const int lhi  = lane >> 4;
    const int row0 = blockIdx.x * 64; // 5000 blocks

    // A staging: thread t -> row rw=t>>2, source k-chunk cw=t&3 (8 floats)
    const int rw = tid >> 2, cw = tid & 3;
    const int a_wbyte = rw * 64 + (((cw ^ ((rw >> 1) & 3))) << 4);
    // A frag read: row r=fm*16+l15, chunk lhi; swz chunk = lhi^((r>>1)&3),
    // and (r>>1)&3 == (l15>>1)&3 for all fm (fm*8 ≡ 0 mod 4):
    const int a_rbyte = l15 * 64 + (((lhi ^ ((l15 >> 1) & 3))) << 4);

    f32x4 acc[4][4];
#pragma unroll
    for (int i = 0; i < 4; ++i)
#pragma unroll
        for (int j = 0; j < 4; ++j) acc[i][j] = (f32x4){0.f, 0.f, 0.f, 0.f};

    float4 ar[3][2];   // PD=3 slots; step S lives in slot S%3 (static via unroll)

#define LOADA(slot, S) {                                                        \
        const float* bp = ((S) < 8) ? q : kk_;                                  \
        const float* p  = bp + (size_t)(row0 + rw) * 256 + ((S) & 7) * 32 + cw * 8; \
        ar[slot][0] = *(const float4*)p;                                        \
        ar[slot][1] = *(const float4*)(p + 4);                                  \
    }
#define CVTW(slot, buf) {                                                       \
        bf16x8 pk;                                                              \
        pk[0]=f2bf(ar[slot][0].x); pk[1]=f2bf(ar[slot][0].y);                   \
        pk[2]=f2bf(ar[slot][0].z); pk[3]=f2bf(ar[slot][0].w);                   \
        pk[4]=f2bf(ar[slot][1].x); pk[5]=f2bf(ar[slot][1].y);                   \
        pk[6]=f2bf(ar[slot][1].z); pk[7]=f2bf(ar[slot][1].w);                   \
        *(bf16x8*)((char*)&lds_a[buf][0] + a_wbyte) = pk;                       \
    }
#define BAR() { asm volatile("s_waitcnt lgkmcnt(0)" ::: "memory");              \
                __builtin_amdgcn_s_barrier(); }

    // ---- prologue: slots 0,1,2 <- steps 0,1,2; LDS[0] <- step 0 ----
    LOADA(0, 0); LOADA(1, 1); LOADA(2, 2);
    CVTW(0, 0);
    BAR();

    // ---- 16 steps, fully unrolled (all slot/guard indices static) ----
#pragma unroll
    for (int s = 0; s < 16; ++s) {
        const int rb = s & 1;
        if (s < 15) CVTW((s + 1) % 3, rb ^ 1);   // stage step s+1 into other buf
        if (s < 13) LOADA(s % 3, s + 3);         // refill freed slot with step s+3
        // B frags: coalesced 16B/lane from L2 (frag id = (wn*4+fn)*16 + s)
        bf16x8 bfr[4];
#pragma unroll
        for (int fn = 0; fn < 4; ++fn)
            bfr[fn] = *(const bf16x8*)(wf +
                ((size_t)(((wn * 4 + fn) * 16 + s) * 64 + lane)) * 8);
#pragma unroll
        for (int fm = 0; fm < 4; ++fm) {
            bf16x8 af = *(const bf16x8*)((const char*)&lds_a[rb][0]
                                         + a_rbyte + fm * 1024);
#pragma unroll
            for (int fn = 0; fn < 4; ++fn)
                acc[fm][fn] = __builtin_amdgcn_mfma_f32_16x16x32_bf16(
                    af, bfr[fn], acc[fm][fn], 0, 0, 0);
        }
        if (s < 15) BAR();
    }
#undef LOADA
#undef CVTW
#undef BAR

    // ---- epilogue: bias + lrelu + dot(w2) + exp + atomicAdd(segsum) ----
    float bias[4], w2v[4];
#pragma unroll
    for (int fn = 0; fn < 4; ++fn) {
        int col = wn * 64 + fn * 16 + l15;
        bias[fn] = b1[col];
        w2v[fn]  = w2[col];
    }
#pragma unroll
    for (int fm = 0; fm < 4; ++fm) {
#pragma unroll
        for (int r = 0; r < 4; ++r) {
            int row = row0 + fm * 16 + lhi * 4 + r;   // C/D: row=(l>>4)*4+reg
            float p = 0.f;
#pragma unroll
            for (int fn = 0; fn < 4; ++fn) {
                float y = acc[fm][fn][r] + bias[fn];
                y = (y > 0.f) ? y : 0.01f * y;
                p += y * w2v[fn];
            }
#pragma unroll
            for (int m = 1; m < 16; m <<= 1) p += __shfl_xor(p, m);
            if (l15 == 0) {
                float e = __expf(p);
                attn[(size_t)row * 4 + wn] = e;
                atomicAdd(&segsum[index[row] * 4 + wn], e);
            }
        }
    }
}

__global__ void seg_norm(const float* __restrict__ attn, const int* __restrict__ index,
                         const float* __restrict__ segsum, float* __restrict__ out, int total) {
    int i = blockIdx.x * blockDim.x + threadIdx.x;
    if (i >= total) return;
    int e = i >> 2, h = i & 3;
    out[i] = attn[i] / (segsum[index[e] * 4 + h] + 1e-16f);
}

extern "C" void kernel_launch(void* const* d_in, const int* in_sizes, int n_in,
                              void* d_out, int out_size, void* d_ws, size_t ws_size,
                              hipStream_t stream) {
    const float* q   = (const float*)d_in[0];
    const float* k   = (const float*)d_in[1];
    const float* w1  = (const float*)d_in[2];
    const float* b1  = (const float*)d_in[3];
    const float* w2  = (const float*)d_in[4];
    const int* index = (const int*)d_in[5];

    const int nE = in_sizes[0] / 256;      // 320000
    char* ws = (char*)d_ws;
    float* attn   = (float*)ws;            ws += (size_t)nE * 4 * 4;
    float* segsum = (float*)ws;            ws += (size_t)NNODES * 4 * 4;
    short* wf     = (short*)ws;            // 256*512 bf16 = 256KB, frag-ordered
    float* out    = (float*)d_out;

    w1_frag<<<256, 64, 0, stream>>>(w1, wf);
    seg_init<<<(NNODES * 4 + 255) / 256, 256, 0, stream>>>(segsum, NNODES * 4);

    attn_gemm<<<nE / 64, 256, 0, stream>>>(q, k, wf, b1, w2, index, attn, segsum);

    int total = nE * 4;
    seg_norm<<<(total + 255) / 256, 256, 0, stream>>>(attn, index, segsum, out, total);
}